// Round 16
// baseline (4083.016 us; speedup 1.0000x reference)
//
#include <hip/hip_runtime.h>
#include <math.h>

#define NB 32
#define NS 400
#define NM 400
#define NH 200
#define NP 16
#define NT 4
#define NBS (NB*NS)          // 12800
#define NPH (NP*NH)          // 3200
#define NPH2 3328            // padded N (13*256)
#define NJT 13               // NPH2/256
#define NX  (2*NM)           // 800
#define NG  (4*NH)           // 800
#define NR  (2*NM+NH)        // 1000
#define K1  1216             // m1 GEMM K' (3*400=1200 padded to /32)
#define K2  608              // m2 GEMM K' (3*200=600 padded to /32)

typedef __attribute__((ext_vector_type(8))) short short8v;
typedef __attribute__((ext_vector_type(4))) float f32x4;
typedef __attribute__((ext_vector_type(4))) unsigned short us4;
typedef unsigned short ushort;

__device__ __forceinline__ float sigf(float x){ return 1.0f/(1.0f+expf(-x)); }

__device__ __forceinline__ ushort f2bf(float x){
  union{float f; unsigned u;} v; v.f=x;
  unsigned r = v.u + 0x7fffu + ((v.u>>16)&1u);
  return (ushort)(r>>16);
}
__device__ __forceinline__ float bf2f(ushort u){
  union{float f; unsigned v;} x; x.v = ((unsigned)u)<<16; return x.f;
}
__device__ __forceinline__ float wave_sum(float v){
  #pragma unroll
  for (int o=32;o>0;o>>=1) v += __shfl_xor(v, o);
  return v;
}

// ---------------- init: h=c=0, sprev=0, eprev=sum(mask)-1 ----------------
__global__ __launch_bounds__(256) void init_kernel(const float* __restrict__ mask,
    float* __restrict__ h, float* __restrict__ c,
    int* __restrict__ sprev, int* __restrict__ eprev){
  int b = blockIdx.x, tid = threadIdx.x;
  __shared__ float red[256];
  float s = 0.f;
  for (int i=tid;i<NS;i+=256) s += mask[(size_t)b*NS+i];
  red[tid]=s; __syncthreads();
  for (int st=128;st>0;st>>=1){ if(tid<st) red[tid]+=red[tid+st]; __syncthreads(); }
  if (tid==0){ sprev[b]=0; eprev[b]=(int)red[0]-1; }
  for (int i=tid;i<NH;i+=256){ h[(size_t)b*NH+i]=0.f; c[(size_t)b*NH+i]=0.f; }
}

// ---------------- conversions / prep ----------------
// mod [12800][400] f32 -> modExp [12800][1216] bf16 [hi|lo|hi|0]
__global__ __launch_bounds__(256) void conv_mod_k(const float* __restrict__ in, ushort* __restrict__ out){
  for (size_t i = (size_t)blockIdx.x*256+threadIdx.x; i < (size_t)NBS*K1; i += (size_t)gridDim.x*256){
    int r = (int)(i/K1), k = (int)(i%K1);
    ushort v = 0;
    if (k < 3*NM){
      float x = in[(size_t)r*NM + (k % NM)];
      ushort h = f2bf(x);
      v = (k < NM || k >= 2*NM) ? h : f2bf(x - bf2f(h));
    }
    out[i] = v;
  }
}
// W1 [3200][600] -> W1exp [3328][1216] rows permuted jp=h*16+p, [hi|hi|lo|0]; rows>=3200 zero
__global__ __launch_bounds__(256) void conv_w1_k(const float* __restrict__ in, ushort* __restrict__ out){
  for (size_t i = (size_t)blockIdx.x*256+threadIdx.x; i < (size_t)NPH2*K1; i += (size_t)gridDim.x*256){
    int jp = (int)(i/K1), k = (int)(i%K1);
    ushort v = 0;
    if (jp < NPH && k < 3*NM){
      int j = (jp&15)*NH + (jp>>4);
      float x = in[(size_t)j*(NM+NH) + (k % NM)];
      ushort h = f2bf(x);
      v = (k < 2*NM) ? h : f2bf(x - bf2f(h));
    }
    out[i] = v;
  }
}
// W2 [3200][200] -> W2exp [3328][608]
__global__ __launch_bounds__(256) void conv_w2_k(const float* __restrict__ in, ushort* __restrict__ out){
  for (size_t i = (size_t)blockIdx.x*256+threadIdx.x; i < (size_t)NPH2*K2; i += (size_t)gridDim.x*256){
    int jp = (int)(i/K2), k = (int)(i%K2);
    ushort v = 0;
    if (jp < NPH && k < 3*NH){
      int j = (jp&15)*NH + (jp>>4);
      float x = in[(size_t)j*NH + (k % NH)];
      ushort h = f2bf(x);
      v = (k < 2*NH) ? h : f2bf(x - bf2f(h));
    }
    out[i] = v;
  }
}
// W1rT[k][jp] = W1[j][400+k], jp-permuted; k<200, jp<3200
__global__ __launch_bounds__(256) void conv_w1r_k(const float* __restrict__ in, float* __restrict__ out){
  for (size_t i = (size_t)blockIdx.x*256+threadIdx.x; i < (size_t)NH*NPH; i += (size_t)gridDim.x*256){
    int k = (int)(i/NPH), jp = (int)(i%NPH);
    int hh = jp>>4, p = jp&15, j = p*NH + hh;
    out[i] = in[(size_t)j*(NM+NH) + NM + k];
  }
}
__global__ __launch_bounds__(256) void permv_k(const float* __restrict__ in, float* __restrict__ out){
  int i = blockIdx.x*256+threadIdx.x;
  if (i < NPH) out[(i%NH)*NP + i/NH] = in[i];
  else if (i < NPH2) out[i] = 0.f;
}
__global__ __launch_bounds__(256) void pad_zero_k(ushort* __restrict__ p, int stride, int start, int width, int rows){
  for (size_t i = (size_t)blockIdx.x*256+threadIdx.x; i < (size_t)rows*width; i += (size_t)gridDim.x*256){
    int r = (int)(i/width), j = (int)(i%width);
    p[(size_t)r*stride + start + j] = 0;
  }
}

// ---------------- LSTM gates (wave per gate) ----------------
__global__ __launch_bounds__(256) void lstm_gates(const float* __restrict__ mod,
    const int* __restrict__ sprev, const int* __restrict__ eprev,
    const float* __restrict__ h,
    const float* __restrict__ Wih, const float* __restrict__ Whh,
    const float* __restrict__ bih, const float* __restrict__ bhh,
    float* __restrict__ gs){
  int b=blockIdx.x, tid=threadIdx.x;
  __shared__ float xs[NX+NH];
  const float* us = mod + ((size_t)b*NS + sprev[b])*NM;
  const float* ue = mod + ((size_t)b*NS + eprev[b])*NM;
  for (int i=tid;i<NM;i+=256){ xs[i]=us[i]; xs[NM+i]=ue[i]; }
  for (int i=tid;i<NH;i+=256) xs[NX+i]=h[(size_t)b*NH+i];
  __syncthreads();
  int w=tid>>6, lane=tid&63;
  int j = blockIdx.y*4 + w;                 // gridDim.y = 200 -> j < 800
  const float* wih = Wih + (size_t)j*NX;
  const float* whh = Whh + (size_t)j*NH;
  float acc=0.f;
  for (int k=lane;k<NX;k+=64) acc += xs[k]*wih[k];
  for (int k=lane;k<NH;k+=64) acc += xs[NX+k]*whh[k];
  acc = wave_sum(acc);
  if (lane==0) gs[(size_t)b*NG+j] = acc + bih[j] + bhh[j];
}
__global__ __launch_bounds__(256) void lstm_update(const float* __restrict__ gs,
    float* __restrict__ h, float* __restrict__ c){
  int b=blockIdx.x, j=threadIdx.x;
  if (j<NH){
    float iv=gs[(size_t)b*NG+j], fv=gs[(size_t)b*NG+NH+j];
    float gv=gs[(size_t)b*NG+2*NH+j], ov=gs[(size_t)b*NG+3*NH+j];
    float c2 = sigf(fv)*c[(size_t)b*NH+j] + sigf(iv)*tanhf(gv);
    c[(size_t)b*NH+j]=c2;
    h[(size_t)b*NH+j]=sigf(ov)*tanhf(c2);
  }
}

// ---------------- r = tanh([h,us,ue]@rW^T), wave per output ----------------
__global__ __launch_bounds__(256) void r_kernel(const float* __restrict__ mod,
    const int* __restrict__ sprev, const int* __restrict__ eprev,
    const float* __restrict__ h, const float* __restrict__ rW,
    float* __restrict__ rbuf){
  int b=blockIdx.x, tid=threadIdx.x;
  __shared__ float zs[NR];
  const float* us = mod + ((size_t)b*NS + sprev[b])*NM;
  const float* ue = mod + ((size_t)b*NS + eprev[b])*NM;
  for (int i=tid;i<NH;i+=256) zs[i]=h[(size_t)b*NH+i];
  for (int i=tid;i<NM;i+=256){ zs[NH+i]=us[i]; zs[NH+NM+i]=ue[i]; }
  __syncthreads();
  int w=tid>>6, lane=tid&63;
  int j = blockIdx.y*4 + w;                 // gridDim.y = 50 -> j < 200
  const float* wr = rW + (size_t)j*NR;
  float acc=0.f;
  for (int k=lane;k<NR;k+=64) acc += zs[k]*wr[k];
  acc = wave_sum(acc);
  if (lane==0) rbuf[(size_t)b*NH+j] = tanhf(acc);
}

// ---------------- prer[b][jp] = b1p[jp] + sum_k r[b][k]*W1rT[k][jp]; padded N ----------------
__global__ __launch_bounds__(256) void prer_kernel(const float* __restrict__ rbuf,
    const float* __restrict__ W1rT, const float* __restrict__ b1p,
    float* __restrict__ prer){
  int b=blockIdx.x, tid=threadIdx.x;
  __shared__ float rs[NH];
  if (tid < NH) rs[tid] = rbuf[(size_t)b*NH+tid];
  __syncthreads();
  int jp = blockIdx.y*256 + tid;
  if (jp < NPH2){
    float acc = 0.f;
    if (jp < NPH){
      acc = b1p[jp];
      #pragma unroll 8
      for (int k=0;k<NH;k++) acc += rs[k]*W1rT[(size_t)k*NPH + jp];
    }
    prer[(size_t)b*NPH2 + jp] = acc;
  }
}

// ------------- fused bf16-split GEMM, 256x256 tile, BK=32, 2-slot, 2 blocks/CU -------------
// Residency-isolation experiment vs R15: identical tile/swizzle/order/traffic/math; LDS cut
// 146->68KB (2 slots, outT aliased) so TWO independent blocks share each CU and one block's
// barrier stalls are covered by the other's MFMA phase. Schedule per K-tile t (slot s=t&1):
//   vmcnt(0); s_barrier      -> tile t landed (staged a full iter ago, ~4300cy slack);
//                               slot s^1's readers (iter t-1) completed before this barrier
//   stage(s^1, t+1)          -> WAR-safe per above
//   12 ds_read + 32 MFMA (setprio)
// MODE 0: bias=prer per-b -> m1exp ushort[12800][608]; MODE 1: bias=b2p -> m2f f32.
template<int MODE>
__global__ __launch_bounds__(512, 2) void gemm_fused(
    const ushort* __restrict__ A, const ushort* __restrict__ W,
    const float* __restrict__ bias, void* __restrict__ outp){
  constexpr int LDK = (MODE==1) ? K2 : K1;
  constexpr int NTI = LDK/32;                // 38 or 19
  struct SMs { ushort A[2][256*32]; ushort B[2][256*32]; };
  union SMu { SMs s; float outT[256][16]; };
  __shared__ SMu sm;                          // 64 KB (outT aliased)
  __shared__ float biasLds[2][256];
  const int tid = threadIdx.x;
  // bijective XCD-chunked swizzle; i-major j-fast for L2 A-panel reuse
  const int nwg = gridDim.x;
  const int q = nwg >> 3, r = nwg & 7;
  const int xcd = blockIdx.x & 7, sub = blockIdx.x >> 3;
  const int wkid = (xcd < r) ? (xcd*(q+1) + sub) : (r*(q+1) + (xcd-r)*q + sub);
  const int i0 = (wkid / NJT) * 256, j0 = (wkid % NJT) * 256;
  const int b0 = i0/NS;
  if (MODE==0){
    if (tid<256) biasLds[0][tid] = bias[(size_t)b0*NPH2 + j0 + tid];
    else { int b1r=(i0+255)/NS; biasLds[1][tid-256] = bias[(size_t)b1r*NPH2 + j0 + (tid-256)]; }
  } else {
    if (tid<256) biasLds[0][tid] = bias[j0+tid];
  }
  const int w = tid>>6, l = tid&63;
  const int wr = w>>2, wc = w&3;            // 2M x 4N waves, wave tile 128x64
  const int fr = l&15, fk = l>>4;
  // staging: wave w stages rows [w*32, w*32+32); 4 lanes/row, 16B/lane.
  // global col slot = phys slot ^ ((row>>1)&3); invariant under row+16.
  const int srow = w*32 + (l>>2);
  const int sslot = l&3;
  const int swzc = (sslot ^ ((srow>>1)&3))*8;   // ushort units
  const ushort* gA0 = A + (size_t)(i0+srow)*LDK + swzc;
  const ushort* gB0 = W + (size_t)(j0+srow)*LDK + swzc;
  const int ldsOff = srow*32 + sslot*8;     // == w*1024 + l*8 : linear in lane
  auto stage = [&](int slot, int kt){
    const ushort* a = gA0 + kt*32;
    const ushort* b = gB0 + kt*32;
    __builtin_amdgcn_global_load_lds((const __attribute__((address_space(1))) void*)a,
        (__attribute__((address_space(3))) void*)(&sm.s.A[slot][ldsOff]), 16, 0, 0);
    __builtin_amdgcn_global_load_lds((const __attribute__((address_space(1))) void*)(a + 16*LDK),
        (__attribute__((address_space(3))) void*)(&sm.s.A[slot][ldsOff + 16*32]), 16, 0, 0);
    __builtin_amdgcn_global_load_lds((const __attribute__((address_space(1))) void*)b,
        (__attribute__((address_space(3))) void*)(&sm.s.B[slot][ldsOff]), 16, 0, 0);
    __builtin_amdgcn_global_load_lds((const __attribute__((address_space(1))) void*)(b + 16*LDK),
        (__attribute__((address_space(3))) void*)(&sm.s.B[slot][ldsOff + 16*32]), 16, 0, 0);
  };
  f32x4 acc[8][4] = {};
  stage(0,0);
  for (int t=0; t<NTI; t++){
    const int s = t&1;
    // tile t landed (staged one full iteration ago); collective barrier also certifies
    // that every wave finished reading slot s^1 (their iter t-1 reads preceded it).
    asm volatile("s_waitcnt vmcnt(0)\n\ts_barrier" ::: "memory");
    if (t+1 < NTI) stage(s^1, t+1);
    short8v a[8], b[4];
    #pragma unroll
    for (int m=0;m<8;m++){
      int row = wr*128 + m*16 + fr;
      a[m] = *(const short8v*)&sm.s.A[s][row*32 + ((fk ^ ((row>>1)&3))*8)];
    }
    #pragma unroll
    for (int n=0;n<4;n++){
      int row = wc*64 + n*16 + fr;
      b[n] = *(const short8v*)&sm.s.B[s][row*32 + ((fk ^ ((row>>1)&3))*8)];
    }
    __builtin_amdgcn_s_setprio(1);
    #pragma unroll
    for (int m=0;m<8;m++)
      #pragma unroll
      for (int n=0;n<4;n++)
        acc[m][n] = __builtin_amdgcn_mfma_f32_16x16x32_bf16(a[m], b[n], acc[m][n], 0,0,0);
    __builtin_amdgcn_s_setprio(0);
  }
  __syncthreads();   // all loads/reads drained (last stage consumed at t=NTI-1) -> outT may alias
  // epilogue: bias + max over the 16 cols (=p) of each 16x16 fragment
  const int blim = (b0+1)*NS;
  #pragma unroll
  for (int m=0;m<8;m++){
    #pragma unroll
    for (int n=0;n<4;n++){
      int colL = wc*64 + n*16 + fr;
      int rbase = wr*128 + m*16 + fk*4;
      #pragma unroll
      for (int reg=0; reg<4; reg++){
        int rowL = rbase + reg;
        float bv = (MODE==0 && (i0+rowL) >= blim) ? biasLds[1][colL] : biasLds[0][colL];
        float v = acc[m][n][reg] + bv;
        v = fmaxf(v, __shfl_xor(v,1));
        v = fmaxf(v, __shfl_xor(v,2));
        v = fmaxf(v, __shfl_xor(v,4));
        v = fmaxf(v, __shfl_xor(v,8));
        if (fr==0) sm.outT[rowL][wc*4+n] = v;
      }
    }
  }
  __syncthreads();
  {
    int rowL = tid>>1;
    int hloc0 = (tid&1)*8;
    int hg0 = (j0>>4) + hloc0;
    if (hg0 < NH){
      int absrow = i0 + rowL;
      float v[8];
      #pragma unroll
      for (int qq=0;qq<8;qq++) v[qq] = sm.outT[rowL][hloc0+qq];
      if (MODE==0){
        ushort* o = (ushort*)outp + (size_t)absrow*K2 + hg0;
        ushort hi[8], lo[8];
        #pragma unroll
        for (int qq=0;qq<8;qq++){ hi[qq]=f2bf(v[qq]); lo[qq]=f2bf(v[qq]-bf2f(hi[qq])); }
        *(us4*)(o)        = (us4){hi[0],hi[1],hi[2],hi[3]};
        *(us4*)(o+4)      = (us4){hi[4],hi[5],hi[6],hi[7]};
        *(us4*)(o+NH)     = (us4){lo[0],lo[1],lo[2],lo[3]};
        *(us4*)(o+NH+4)   = (us4){lo[4],lo[5],lo[6],lo[7]};
        *(us4*)(o+2*NH)   = (us4){hi[0],hi[1],hi[2],hi[3]};
        *(us4*)(o+2*NH+4) = (us4){hi[4],hi[5],hi[6],hi[7]};
      } else {
        float* o = (float*)outp + (size_t)absrow*NH + hg0;
        *(f32x4*)o     = (f32x4){v[0],v[1],v[2],v[3]};
        *(f32x4*)(o+4) = (f32x4){v[4],v[5],v[6],v[7]};
      }
    }
  }
}

// --------- logits main v2: thread per (s,p); grid (NB, 25) = 800 blocks ---------
// W3 staged in LDS (row stride 401 floats: 16 per-k addresses hit 16 distinct banks).
// Per-(s,p) accumulation order identical to v1 -> bit-identical logits.
__global__ __launch_bounds__(256) void logits_main(const ushort* __restrict__ m1e,
    const float* __restrict__ m2, const float* __restrict__ W3, const float* __restrict__ b3,
    const float* __restrict__ mask, float* __restrict__ lg){
  __shared__ float w3s[NP][2*NH+1];     // 16 x 401 floats
  int b = blockIdx.x, tid = threadIdx.x;
  for (int e = tid; e < NP*2*NH; e += 256)
    w3s[e/(2*NH)][e%(2*NH)] = W3[e];
  __syncthreads();
  int sl = tid >> 4, p = tid & 15;
  int s = blockIdx.y*16 + sl;           // 25*16 = 400 exactly
  const ushort* a = m1e + (size_t)(b*NS+s)*K2;
  const float4* d = (const float4*)(m2 + (size_t)(b*NS+s)*NH);
  float acc = b3[p];
  const float* wp = &w3s[p][0];
  for (int k=0;k<NH/4;k++){
    us4 hv = *(const us4*)(a + 4*k);
    us4 lv = *(const us4*)(a + NH + 4*k);
    float4 dv = d[k];
    float a0=bf2f(hv.x)+bf2f(lv.x), a1=bf2f(hv.y)+bf2f(lv.y);
    float a2=bf2f(hv.z)+bf2f(lv.z), a3=bf2f(hv.w)+bf2f(lv.w);
    const float* w = wp + 4*k;
    acc += a0*w[0]+a1*w[1]+a2*w[2]+a3*w[3];
    const float* w2 = w + NH;
    acc += dv.x*w2[0]+dv.y*w2[1]+dv.z*w2[2]+dv.w*w2[3];
  }
  float best = acc;
  best = fmaxf(best, __shfl_xor(best,1));
  best = fmaxf(best, __shfl_xor(best,2));
  best = fmaxf(best, __shfl_xor(best,4));
  best = fmaxf(best, __shfl_xor(best,8));
  if (p == 0)
    lg[(size_t)b*NS+s] = (mask[(size_t)b*NS+s] > 0.f) ? best : -1e30f;
}

// --------- logits finish: log_softmax + argmax; one block per b ---------
__global__ __launch_bounds__(256) void logits_fin(const float* __restrict__ lg,
    float* __restrict__ out, int t, int* __restrict__ prevIdx){
  int b=blockIdx.x, tid=threadIdx.x;
  __shared__ float rv[256]; __shared__ int ri[256]; __shared__ float sv[256];
  float bv=-INFINITY; int bi=NS;
  for (int s=tid;s<NS;s+=256){ float v=lg[(size_t)b*NS+s]; if (v>bv){bv=v;bi=s;} }
  rv[tid]=bv; ri[tid]=bi; __syncthreads();
  for (int st=128;st>0;st>>=1){
    if (tid<st){
      float v2=rv[tid+st]; int i2=ri[tid+st];
      if (v2>rv[tid] || (v2==rv[tid] && i2<ri[tid])){ rv[tid]=v2; ri[tid]=i2; }
    }
    __syncthreads();
  }
  float mx = rv[0];
  float ps=0.f;
  for (int s=tid;s<NS;s+=256) ps += expf(lg[(size_t)b*NS+s]-mx);
  sv[tid]=ps; __syncthreads();
  for (int st=128;st>0;st>>=1){ if (tid<st) sv[tid]+=sv[tid+st]; __syncthreads(); }
  float lse = mx + logf(sv[0]);
  for (int s=tid;s<NS;s+=256) out[((size_t)b*NT + t)*NS + s] = lg[(size_t)b*NS+s]-lse;
  if (tid==0) prevIdx[b]=ri[0];
}

// =============================== host ===============================
extern "C" void kernel_launch(void* const* d_in, const int* in_sizes, int n_in,
                              void* d_out, int out_size, void* d_ws, size_t ws_size,
                              hipStream_t stream){
  const float* mod  = (const float*)d_in[1];
  const float* mask = (const float*)d_in[2];
  const float* Wih  = (const float*)d_in[3];
  const float* Whh  = (const float*)d_in[4];
  const float* bih  = (const float*)d_in[5];
  const float* bhh  = (const float*)d_in[6];
  const float* rW[2] = {(const float*)d_in[7],  (const float*)d_in[14]};
  const float* W1[2] = {(const float*)d_in[8],  (const float*)d_in[15]};
  const float* b1[2] = {(const float*)d_in[9],  (const float*)d_in[16]};
  const float* W2[2] = {(const float*)d_in[10], (const float*)d_in[17]};
  const float* b2[2] = {(const float*)d_in[11], (const float*)d_in[18]};
  const float* W3[2] = {(const float*)d_in[12], (const float*)d_in[19]};
  const float* b3[2] = {(const float*)d_in[13], (const float*)d_in[20]};
  float* out[2];
  out[0] = (float*)d_out;
  out[1] = out[0] + (size_t)NB*NT*NS;

  float* wsf = (float*)d_ws;
  size_t off = 0;
  auto carve = [&](size_t n)->size_t{ size_t o=off; off += (n + 63) & ~(size_t)63; return o; };
  float* hbuf   = wsf + carve((size_t)NB*NH);
  float* cbuf   = wsf + carve((size_t)NB*NH);
  float* prer   = wsf + carve((size_t)NB*NPH2);
  int*   sprev  = (int*)(wsf + carve(128));
  int*   eprev  = sprev + 32;
  float* m2f    = wsf + carve((size_t)NBS*NH);
  float* b2p[2] = {wsf + carve(NPH2), wsf + carve(NPH2)};
  float* b1p[2] = {wsf + carve(NPH2), wsf + carve(NPH2)};
  float* rbuf   = wsf + carve((size_t)NB*NH);
  float* gsbuf  = wsf + carve((size_t)NB*NG);
  float* lgbuf  = wsf + carve((size_t)NB*NS);
  float* W1rT[2]= {wsf + carve((size_t)NH*NPH), wsf + carve((size_t)NH*NPH)};
  ushort* modExp   = (ushort*)(wsf + carve((size_t)NBS*K1/2));
  ushort* W1exp[2] = {(ushort*)(wsf + carve((size_t)NPH2*K1/2)),
                      (ushort*)(wsf + carve((size_t)NPH2*K1/2))};
  ushort* W2exp[2] = {(ushort*)(wsf + carve((size_t)NPH2*K2/2)),
                      (ushort*)(wsf + carve((size_t)NPH2*K2/2))};
  ushort* m1exp    = (ushort*)(wsf + carve((size_t)NBS*K2/2));

  // ---- init + prep (every launch; deterministic) ----
  init_kernel<<<NB, 256, 0, stream>>>(mask, hbuf, cbuf, sprev, eprev);
  conv_mod_k<<<2048, 256, 0, stream>>>(mod, modExp);
  pad_zero_k<<<128, 256, 0, stream>>>(m1exp, K2, 3*NH, K2-3*NH, NBS);
  for (int net=0; net<2; net++){
    conv_w1_k<<<1024, 256, 0, stream>>>(W1[net], W1exp[net]);
    conv_w2_k<<<512, 256, 0, stream>>>(W2[net], W2exp[net]);
    conv_w1r_k<<<1024, 256, 0, stream>>>(W1[net], W1rT[net]);
    permv_k<<<(NPH2+255)/256, 256, 0, stream>>>(b2[net], b2p[net]);
    permv_k<<<(NPH2+255)/256, 256, 0, stream>>>(b1[net], b1p[net]);
  }

  const int GFULL = (NBS/256) * NJT;              // 50*13 = 650
  for (int t=0; t<NT; t++){
    lstm_gates<<<dim3(NB, NG/4), 256, 0, stream>>>(mod, sprev, eprev, hbuf,
                                                   Wih, Whh, bih, bhh, gsbuf);
    lstm_update<<<NB, 256, 0, stream>>>(gsbuf, hbuf, cbuf);
    for (int net=0; net<2; net++){
      r_kernel<<<dim3(NB, NH/4), 256, 0, stream>>>(mod, sprev, eprev, hbuf, rW[net], rbuf);
      prer_kernel<<<dim3(NB, NPH2/256), 256, 0, stream>>>(rbuf, W1rT[net], b1p[net], prer);
      gemm_fused<0><<<GFULL, 512, 0, stream>>>(modExp, W1exp[net], prer, (void*)m1exp);
      gemm_fused<1><<<GFULL, 512, 0, stream>>>(m1exp, W2exp[net], b2p[net], (void*)m2f);
      logits_main<<<dim3(NB, NS/16), 256, 0, stream>>>(m1exp, m2f, W3[net], b3[net], mask, lgbuf);
      logits_fin<<<NB, 256, 0, stream>>>(lgbuf, out[net], t, net==0 ? sprev : eprev);
    }
  }
}

// Round 17
// 2599.442 us; speedup vs baseline: 1.5707x; 1.5707x over previous
//
#include <hip/hip_runtime.h>
#include <math.h>

#define NB 32
#define NS 400
#define NM 400
#define NH 200
#define NP 16
#define NT 4
#define NBS (NB*NS)          // 12800
#define NPH (NP*NH)          // 3200
#define NPH2 3328            // padded N (13*256)
#define NJT 13               // NPH2/256
#define NX  (2*NM)           // 800
#define NG  (4*NH)           // 800
#define NR  (2*NM+NH)        // 1000
#define K1  1216             // m1 GEMM K' (3*400=1200 padded to /32)
#define K2  608              // m2 GEMM K' (3*200=600 padded to /32)

typedef __attribute__((ext_vector_type(8))) short short8v;
typedef __attribute__((ext_vector_type(4))) float f32x4;
typedef __attribute__((ext_vector_type(4))) unsigned short us4;
typedef unsigned short ushort;

__device__ __forceinline__ float sigf(float x){ return 1.0f/(1.0f+expf(-x)); }

__device__ __forceinline__ ushort f2bf(float x){
  union{float f; unsigned u;} v; v.f=x;
  unsigned r = v.u + 0x7fffu + ((v.u>>16)&1u);
  return (ushort)(r>>16);
}
__device__ __forceinline__ float bf2f(ushort u){
  union{float f; unsigned v;} x; x.v = ((unsigned)u)<<16; return x.f;
}
__device__ __forceinline__ float wave_sum(float v){
  #pragma unroll
  for (int o=32;o>0;o>>=1) v += __shfl_xor(v, o);
  return v;
}

// ---------------- init: h=c=0, sprev=0, eprev=sum(mask)-1 ----------------
__global__ __launch_bounds__(256) void init_kernel(const float* __restrict__ mask,
    float* __restrict__ h, float* __restrict__ c,
    int* __restrict__ sprev, int* __restrict__ eprev){
  int b = blockIdx.x, tid = threadIdx.x;
  __shared__ float red[256];
  float s = 0.f;
  for (int i=tid;i<NS;i+=256) s += mask[(size_t)b*NS+i];
  red[tid]=s; __syncthreads();
  for (int st=128;st>0;st>>=1){ if(tid<st) red[tid]+=red[tid+st]; __syncthreads(); }
  if (tid==0){ sprev[b]=0; eprev[b]=(int)red[0]-1; }
  for (int i=tid;i<NH;i+=256){ h[(size_t)b*NH+i]=0.f; c[(size_t)b*NH+i]=0.f; }
}

// ---------------- conversions / prep ----------------
// mod [12800][400] f32 -> modExp [12800][1216] bf16 [hi|lo|hi|0]
__global__ __launch_bounds__(256) void conv_mod_k(const float* __restrict__ in, ushort* __restrict__ out){
  for (size_t i = (size_t)blockIdx.x*256+threadIdx.x; i < (size_t)NBS*K1; i += (size_t)gridDim.x*256){
    int r = (int)(i/K1), k = (int)(i%K1);
    ushort v = 0;
    if (k < 3*NM){
      float x = in[(size_t)r*NM + (k % NM)];
      ushort h = f2bf(x);
      v = (k < NM || k >= 2*NM) ? h : f2bf(x - bf2f(h));
    }
    out[i] = v;
  }
}
// W1 [3200][600] -> W1exp [3328][1216] rows permuted jp=h*16+p, [hi|hi|lo|0]; rows>=3200 zero
__global__ __launch_bounds__(256) void conv_w1_k(const float* __restrict__ in, ushort* __restrict__ out){
  for (size_t i = (size_t)blockIdx.x*256+threadIdx.x; i < (size_t)NPH2*K1; i += (size_t)gridDim.x*256){
    int jp = (int)(i/K1), k = (int)(i%K1);
    ushort v = 0;
    if (jp < NPH && k < 3*NM){
      int j = (jp&15)*NH + (jp>>4);
      float x = in[(size_t)j*(NM+NH) + (k % NM)];
      ushort h = f2bf(x);
      v = (k < 2*NM) ? h : f2bf(x - bf2f(h));
    }
    out[i] = v;
  }
}
// W2 [3200][200] -> W2exp [3328][608]
__global__ __launch_bounds__(256) void conv_w2_k(const float* __restrict__ in, ushort* __restrict__ out){
  for (size_t i = (size_t)blockIdx.x*256+threadIdx.x; i < (size_t)NPH2*K2; i += (size_t)gridDim.x*256){
    int jp = (int)(i/K2), k = (int)(i%K2);
    ushort v = 0;
    if (jp < NPH && k < 3*NH){
      int j = (jp&15)*NH + (jp>>4);
      float x = in[(size_t)j*NH + (k % NH)];
      ushort h = f2bf(x);
      v = (k < 2*NH) ? h : f2bf(x - bf2f(h));
    }
    out[i] = v;
  }
}
// W1rT[k][jp] = W1[j][400+k], jp-permuted; k<200, jp<3200
__global__ __launch_bounds__(256) void conv_w1r_k(const float* __restrict__ in, float* __restrict__ out){
  for (size_t i = (size_t)blockIdx.x*256+threadIdx.x; i < (size_t)NH*NPH; i += (size_t)gridDim.x*256){
    int k = (int)(i/NPH), jp = (int)(i%NPH);
    int hh = jp>>4, p = jp&15, j = p*NH + hh;
    out[i] = in[(size_t)j*(NM+NH) + NM + k];
  }
}
__global__ __launch_bounds__(256) void permv_k(const float* __restrict__ in, float* __restrict__ out){
  int i = blockIdx.x*256+threadIdx.x;
  if (i < NPH) out[(i%NH)*NP + i/NH] = in[i];
  else if (i < NPH2) out[i] = 0.f;
}
__global__ __launch_bounds__(256) void pad_zero_k(ushort* __restrict__ p, int stride, int start, int width, int rows){
  for (size_t i = (size_t)blockIdx.x*256+threadIdx.x; i < (size_t)rows*width; i += (size_t)gridDim.x*256){
    int r = (int)(i/width), j = (int)(i%width);
    p[(size_t)r*stride + start + j] = 0;
  }
}

// ---------------- LSTM gates (wave per gate) ----------------
__global__ __launch_bounds__(256) void lstm_gates(const float* __restrict__ mod,
    const int* __restrict__ sprev, const int* __restrict__ eprev,
    const float* __restrict__ h,
    const float* __restrict__ Wih, const float* __restrict__ Whh,
    const float* __restrict__ bih, const float* __restrict__ bhh,
    float* __restrict__ gs){
  int b=blockIdx.x, tid=threadIdx.x;
  __shared__ float xs[NX+NH];
  const float* us = mod + ((size_t)b*NS + sprev[b])*NM;
  const float* ue = mod + ((size_t)b*NS + eprev[b])*NM;
  for (int i=tid;i<NM;i+=256){ xs[i]=us[i]; xs[NM+i]=ue[i]; }
  for (int i=tid;i<NH;i+=256) xs[NX+i]=h[(size_t)b*NH+i];
  __syncthreads();
  int w=tid>>6, lane=tid&63;
  int j = blockIdx.y*4 + w;                 // gridDim.y = 200 -> j < 800
  const float* wih = Wih + (size_t)j*NX;
  const float* whh = Whh + (size_t)j*NH;
  float acc=0.f;
  for (int k=lane;k<NX;k+=64) acc += xs[k]*wih[k];
  for (int k=lane;k<NH;k+=64) acc += xs[NX+k]*whh[k];
  acc = wave_sum(acc);
  if (lane==0) gs[(size_t)b*NG+j] = acc + bih[j] + bhh[j];
}
__global__ __launch_bounds__(256) void lstm_update(const float* __restrict__ gs,
    float* __restrict__ h, float* __restrict__ c){
  int b=blockIdx.x, j=threadIdx.x;
  if (j<NH){
    float iv=gs[(size_t)b*NG+j], fv=gs[(size_t)b*NG+NH+j];
    float gv=gs[(size_t)b*NG+2*NH+j], ov=gs[(size_t)b*NG+3*NH+j];
    float c2 = sigf(fv)*c[(size_t)b*NH+j] + sigf(iv)*tanhf(gv);
    c[(size_t)b*NH+j]=c2;
    h[(size_t)b*NH+j]=sigf(ov)*tanhf(c2);
  }
}

// ---------------- r = tanh([h,us,ue]@rW^T), wave per output ----------------
__global__ __launch_bounds__(256) void r_kernel(const float* __restrict__ mod,
    const int* __restrict__ sprev, const int* __restrict__ eprev,
    const float* __restrict__ h, const float* __restrict__ rW,
    float* __restrict__ rbuf){
  int b=blockIdx.x, tid=threadIdx.x;
  __shared__ float zs[NR];
  const float* us = mod + ((size_t)b*NS + sprev[b])*NM;
  const float* ue = mod + ((size_t)b*NS + eprev[b])*NM;
  for (int i=tid;i<NH;i+=256) zs[i]=h[(size_t)b*NH+i];
  for (int i=tid;i<NM;i+=256){ zs[NH+i]=us[i]; zs[NH+NM+i]=ue[i]; }
  __syncthreads();
  int w=tid>>6, lane=tid&63;
  int j = blockIdx.y*4 + w;                 // gridDim.y = 50 -> j < 200
  const float* wr = rW + (size_t)j*NR;
  float acc=0.f;
  for (int k=lane;k<NR;k+=64) acc += zs[k]*wr[k];
  acc = wave_sum(acc);
  if (lane==0) rbuf[(size_t)b*NH+j] = tanhf(acc);
}

// ---------------- prer[b][jp] = b1p[jp] + sum_k r[b][k]*W1rT[k][jp]; padded N ----------------
__global__ __launch_bounds__(256) void prer_kernel(const float* __restrict__ rbuf,
    const float* __restrict__ W1rT, const float* __restrict__ b1p,
    float* __restrict__ prer){
  int b=blockIdx.x, tid=threadIdx.x;
  __shared__ float rs[NH];
  if (tid < NH) rs[tid] = rbuf[(size_t)b*NH+tid];
  __syncthreads();
  int jp = blockIdx.y*256 + tid;
  if (jp < NPH2){
    float acc = 0.f;
    if (jp < NPH){
      acc = b1p[jp];
      #pragma unroll 8
      for (int k=0;k<NH;k++) acc += rs[k]*W1rT[(size_t)k*NPH + jp];
    }
    prer[(size_t)b*NPH2 + jp] = acc;
  }
}

// ------------- fused bf16-split GEMM, 256x256 tile, BK=32, 4-slot 3-deep pipeline -------------
// (R7 kernel verbatim — best measured: 173us, conflicts 1.37e6, FETCH 117MB. The counted
// vmcnt(8) 3-deep schedule is load-bearing: it lets waves skew so ds_read bursts interleave;
// drain-to-0 variants re-synchronize waves and multiply bank conflicts 30x — R16.)
// MODE 0: bias=prer per-b -> m1exp ushort[12800][608]; MODE 1: bias=b2p -> m2f f32.
template<int MODE>
__global__ __launch_bounds__(512, 2) void gemm_fused(
    const ushort* __restrict__ A, const ushort* __restrict__ W,
    const float* __restrict__ bias, void* __restrict__ outp){
  constexpr int LDK = (MODE==1) ? K2 : K1;
  constexpr int NTI = LDK/32;                // 38 or 19
  __shared__ __align__(16) ushort As[4][256*32];
  __shared__ __align__(16) ushort Bs[4][256*32];
  __shared__ float biasLds[2][256];
  __shared__ float outT[256][16];
  const int tid = threadIdx.x;
  // bijective XCD-chunked swizzle; i-major j-fast for L2 A-panel reuse
  const int nwg = gridDim.x;
  const int q = nwg >> 3, r = nwg & 7;
  const int xcd = blockIdx.x & 7, sub = blockIdx.x >> 3;
  const int wkid = (xcd < r) ? (xcd*(q+1) + sub) : (r*(q+1) + (xcd-r)*q + sub);
  const int i0 = (wkid / NJT) * 256, j0 = (wkid % NJT) * 256;
  const int b0 = i0/NS;
  if (MODE==0){
    if (tid<256) biasLds[0][tid] = bias[(size_t)b0*NPH2 + j0 + tid];
    else { int b1r=(i0+255)/NS; biasLds[1][tid-256] = bias[(size_t)b1r*NPH2 + j0 + (tid-256)]; }
  } else {
    if (tid<256) biasLds[0][tid] = bias[j0+tid];
  }
  const int w = tid>>6, l = tid&63;
  const int wr = w>>2, wc = w&3;            // 2M x 4N waves, wave tile 128x64
  const int fr = l&15, fk = l>>4;
  // staging: wave w stages rows [w*32, w*32+32); 4 lanes/row, 16B/lane.
  // global col slot = phys slot ^ ((row>>1)&3); invariant under row+16.
  const int srow = w*32 + (l>>2);
  const int sslot = l&3;
  const int swzc = (sslot ^ ((srow>>1)&3))*8;   // ushort units
  const ushort* gA0 = A + (size_t)(i0+srow)*LDK + swzc;
  const ushort* gB0 = W + (size_t)(j0+srow)*LDK + swzc;
  const int ldsOff = srow*32 + sslot*8;     // == w*1024 + l*8 : linear in lane
  auto stage = [&](int slot, int kt){
    const ushort* a = gA0 + kt*32;
    const ushort* b = gB0 + kt*32;
    __builtin_amdgcn_global_load_lds((const __attribute__((address_space(1))) void*)a,
        (__attribute__((address_space(3))) void*)(&As[slot][ldsOff]), 16, 0, 0);
    __builtin_amdgcn_global_load_lds((const __attribute__((address_space(1))) void*)(a + 16*LDK),
        (__attribute__((address_space(3))) void*)(&As[slot][ldsOff + 16*32]), 16, 0, 0);
    __builtin_amdgcn_global_load_lds((const __attribute__((address_space(1))) void*)b,
        (__attribute__((address_space(3))) void*)(&Bs[slot][ldsOff]), 16, 0, 0);
    __builtin_amdgcn_global_load_lds((const __attribute__((address_space(1))) void*)(b + 16*LDK),
        (__attribute__((address_space(3))) void*)(&Bs[slot][ldsOff + 16*32]), 16, 0, 0);
  };
  f32x4 acc[8][4] = {};
  stage(0,0); stage(1,1); stage(2,2);
  for (int t=0; t<NTI; t++){
    // tile t landed (4 loads/wave/tile; t+1,t+2 may stay in flight), collective barrier
    if (t+2 < NTI)      asm volatile("s_waitcnt vmcnt(8)\n\ts_barrier" ::: "memory");
    else if (t+1 < NTI) asm volatile("s_waitcnt vmcnt(4)\n\ts_barrier" ::: "memory");
    else                asm volatile("s_waitcnt vmcnt(0)\n\ts_barrier" ::: "memory");
    const int s = t&3;
    short8v a[8], b[4];
    #pragma unroll
    for (int m=0;m<8;m++){
      int row = wr*128 + m*16 + fr;
      a[m] = *(const short8v*)&As[s][row*32 + ((fk ^ ((row>>1)&3))*8)];
    }
    #pragma unroll
    for (int n=0;n<4;n++){
      int row = wc*64 + n*16 + fr;
      b[n] = *(const short8v*)&Bs[s][row*32 + ((fk ^ ((row>>1)&3))*8)];
    }
    // prefetch tile t+3 into slot (t+3)&3 == (t-1)&3 : its reads retired before this
    // iteration's barrier (consumed by iter t-1 MFMAs), so WAR-safe.
    if (t+3 < NTI) stage((t+3)&3, t+3);
    __builtin_amdgcn_s_setprio(1);
    #pragma unroll
    for (int m=0;m<8;m++)
      #pragma unroll
      for (int n=0;n<4;n++)
        acc[m][n] = __builtin_amdgcn_mfma_f32_16x16x32_bf16(a[m], b[n], acc[m][n], 0,0,0);
    __builtin_amdgcn_s_setprio(0);
  }
  __syncthreads();
  // epilogue: bias + max over the 16 cols (=p) of each 16x16 fragment
  const int blim = (b0+1)*NS;
  #pragma unroll
  for (int m=0;m<8;m++){
    #pragma unroll
    for (int n=0;n<4;n++){
      int colL = wc*64 + n*16 + fr;
      int rbase = wr*128 + m*16 + fk*4;
      #pragma unroll
      for (int reg=0; reg<4; reg++){
        int rowL = rbase + reg;
        float bv = (MODE==0 && (i0+rowL) >= blim) ? biasLds[1][colL] : biasLds[0][colL];
        float v = acc[m][n][reg] + bv;
        v = fmaxf(v, __shfl_xor(v,1));
        v = fmaxf(v, __shfl_xor(v,2));
        v = fmaxf(v, __shfl_xor(v,4));
        v = fmaxf(v, __shfl_xor(v,8));
        if (fr==0) outT[rowL][wc*4+n] = v;
      }
    }
  }
  __syncthreads();
  {
    int rowL = tid>>1;
    int hloc0 = (tid&1)*8;
    int hg0 = (j0>>4) + hloc0;
    if (hg0 < NH){
      int absrow = i0 + rowL;
      float v[8];
      #pragma unroll
      for (int qq=0;qq<8;qq++) v[qq] = outT[rowL][hloc0+qq];
      if (MODE==0){
        ushort* o = (ushort*)outp + (size_t)absrow*K2 + hg0;
        ushort hi[8], lo[8];
        #pragma unroll
        for (int qq=0;qq<8;qq++){ hi[qq]=f2bf(v[qq]); lo[qq]=f2bf(v[qq]-bf2f(hi[qq])); }
        *(us4*)(o)        = (us4){hi[0],hi[1],hi[2],hi[3]};
        *(us4*)(o+4)      = (us4){hi[4],hi[5],hi[6],hi[7]};
        *(us4*)(o+NH)     = (us4){lo[0],lo[1],lo[2],lo[3]};
        *(us4*)(o+NH+4)   = (us4){lo[4],lo[5],lo[6],lo[7]};
        *(us4*)(o+2*NH)   = (us4){hi[0],hi[1],hi[2],hi[3]};
        *(us4*)(o+2*NH+4) = (us4){hi[4],hi[5],hi[6],hi[7]};
      } else {
        float* o = (float*)outp + (size_t)absrow*NH + hg0;
        *(f32x4*)o     = (f32x4){v[0],v[1],v[2],v[3]};
        *(f32x4*)(o+4) = (f32x4){v[4],v[5],v[6],v[7]};
      }
    }
  }
}

// --------- logits main v2: thread per (s,p); grid (NB, 25) = 800 blocks ---------
// W3 staged in LDS (row stride 401 floats: 16 per-k addresses hit 16 distinct banks).
// Per-(s,p) accumulation order identical to v1 -> bit-identical logits.
__global__ __launch_bounds__(256) void logits_main(const ushort* __restrict__ m1e,
    const float* __restrict__ m2, const float* __restrict__ W3, const float* __restrict__ b3,
    const float* __restrict__ mask, float* __restrict__ lg){
  __shared__ float w3s[NP][2*NH+1];     // 16 x 401 floats
  int b = blockIdx.x, tid = threadIdx.x;
  for (int e = tid; e < NP*2*NH; e += 256)
    w3s[e/(2*NH)][e%(2*NH)] = W3[e];
  __syncthreads();
  int sl = tid >> 4, p = tid & 15;
  int s = blockIdx.y*16 + sl;           // 25*16 = 400 exactly
  const ushort* a = m1e + (size_t)(b*NS+s)*K2;
  const float4* d = (const float4*)(m2 + (size_t)(b*NS+s)*NH);
  float acc = b3[p];
  const float* wp = &w3s[p][0];
  for (int k=0;k<NH/4;k++){
    us4 hv = *(const us4*)(a + 4*k);
    us4 lv = *(const us4*)(a + NH + 4*k);
    float4 dv = d[k];
    float a0=bf2f(hv.x)+bf2f(lv.x), a1=bf2f(hv.y)+bf2f(lv.y);
    float a2=bf2f(hv.z)+bf2f(lv.z), a3=bf2f(hv.w)+bf2f(lv.w);
    const float* w = wp + 4*k;
    acc += a0*w[0]+a1*w[1]+a2*w[2]+a3*w[3];
    const float* w2 = w + NH;
    acc += dv.x*w2[0]+dv.y*w2[1]+dv.z*w2[2]+dv.w*w2[3];
  }
  float best = acc;
  best = fmaxf(best, __shfl_xor(best,1));
  best = fmaxf(best, __shfl_xor(best,2));
  best = fmaxf(best, __shfl_xor(best,4));
  best = fmaxf(best, __shfl_xor(best,8));
  if (p == 0)
    lg[(size_t)b*NS+s] = (mask[(size_t)b*NS+s] > 0.f) ? best : -1e30f;
}

// --------- logits finish: log_softmax + argmax; one block per b ---------
__global__ __launch_bounds__(256) void logits_fin(const float* __restrict__ lg,
    float* __restrict__ out, int t, int* __restrict__ prevIdx){
  int b=blockIdx.x, tid=threadIdx.x;
  __shared__ float rv[256]; __shared__ int ri[256]; __shared__ float sv[256];
  float bv=-INFINITY; int bi=NS;
  for (int s=tid;s<NS;s+=256){ float v=lg[(size_t)b*NS+s]; if (v>bv){bv=v;bi=s;} }
  rv[tid]=bv; ri[tid]=bi; __syncthreads();
  for (int st=128;st>0;st>>=1){
    if (tid<st){
      float v2=rv[tid+st]; int i2=ri[tid+st];
      if (v2>rv[tid] || (v2==rv[tid] && i2<ri[tid])){ rv[tid]=v2; ri[tid]=i2; }
    }
    __syncthreads();
  }
  float mx = rv[0];
  float ps=0.f;
  for (int s=tid;s<NS;s+=256) ps += expf(lg[(size_t)b*NS+s]-mx);
  sv[tid]=ps; __syncthreads();
  for (int st=128;st>0;st>>=1){ if (tid<st) sv[tid]+=sv[tid+st]; __syncthreads(); }
  float lse = mx + logf(sv[0]);
  for (int s=tid;s<NS;s+=256) out[((size_t)b*NT + t)*NS + s] = lg[(size_t)b*NS+s]-lse;
  if (tid==0) prevIdx[b]=ri[0];
}

// =============================== host ===============================
extern "C" void kernel_launch(void* const* d_in, const int* in_sizes, int n_in,
                              void* d_out, int out_size, void* d_ws, size_t ws_size,
                              hipStream_t stream){
  const float* mod  = (const float*)d_in[1];
  const float* mask = (const float*)d_in[2];
  const float* Wih  = (const float*)d_in[3];
  const float* Whh  = (const float*)d_in[4];
  const float* bih  = (const float*)d_in[5];
  const float* bhh  = (const float*)d_in[6];
  const float* rW[2] = {(const float*)d_in[7],  (const float*)d_in[14]};
  const float* W1[2] = {(const float*)d_in[8],  (const float*)d_in[15]};
  const float* b1[2] = {(const float*)d_in[9],  (const float*)d_in[16]};
  const float* W2[2] = {(const float*)d_in[10], (const float*)d_in[17]};
  const float* b2[2] = {(const float*)d_in[11], (const float*)d_in[18]};
  const float* W3[2] = {(const float*)d_in[12], (const float*)d_in[19]};
  const float* b3[2] = {(const float*)d_in[13], (const float*)d_in[20]};
  float* out[2];
  out[0] = (float*)d_out;
  out[1] = out[0] + (size_t)NB*NT*NS;

  float* wsf = (float*)d_ws;
  size_t off = 0;
  auto carve = [&](size_t n)->size_t{ size_t o=off; off += (n + 63) & ~(size_t)63; return o; };
  float* hbuf   = wsf + carve((size_t)NB*NH);
  float* cbuf   = wsf + carve((size_t)NB*NH);
  float* prer   = wsf + carve((size_t)NB*NPH2);
  int*   sprev  = (int*)(wsf + carve(128));
  int*   eprev  = sprev + 32;
  float* m2f    = wsf + carve((size_t)NBS*NH);
  float* b2p[2] = {wsf + carve(NPH2), wsf + carve(NPH2)};
  float* b1p[2] = {wsf + carve(NPH2), wsf + carve(NPH2)};
  float* rbuf   = wsf + carve((size_t)NB*NH);
  float* gsbuf  = wsf + carve((size_t)NB*NG);
  float* lgbuf  = wsf + carve((size_t)NB*NS);
  float* W1rT[2]= {wsf + carve((size_t)NH*NPH), wsf + carve((size_t)NH*NPH)};
  ushort* modExp   = (ushort*)(wsf + carve((size_t)NBS*K1/2));
  ushort* W1exp[2] = {(ushort*)(wsf + carve((size_t)NPH2*K1/2)),
                      (ushort*)(wsf + carve((size_t)NPH2*K1/2))};
  ushort* W2exp[2] = {(ushort*)(wsf + carve((size_t)NPH2*K2/2)),
                      (ushort*)(wsf + carve((size_t)NPH2*K2/2))};
  ushort* m1exp    = (ushort*)(wsf + carve((size_t)NBS*K2/2));

  // ---- init + prep (every launch; deterministic) ----
  init_kernel<<<NB, 256, 0, stream>>>(mask, hbuf, cbuf, sprev, eprev);
  conv_mod_k<<<2048, 256, 0, stream>>>(mod, modExp);
  pad_zero_k<<<128, 256, 0, stream>>>(m1exp, K2, 3*NH, K2-3*NH, NBS);
  for (int net=0; net<2; net++){
    conv_w1_k<<<1024, 256, 0, stream>>>(W1[net], W1exp[net]);
    conv_w2_k<<<512, 256, 0, stream>>>(W2[net], W2exp[net]);
    conv_w1r_k<<<1024, 256, 0, stream>>>(W1[net], W1rT[net]);
    permv_k<<<(NPH2+255)/256, 256, 0, stream>>>(b2[net], b2p[net]);
    permv_k<<<(NPH2+255)/256, 256, 0, stream>>>(b1[net], b1p[net]);
  }

  const int GFULL = (NBS/256) * NJT;              // 50*13 = 650
  for (int t=0; t<NT; t++){
    lstm_gates<<<dim3(NB, NG/4), 256, 0, stream>>>(mod, sprev, eprev, hbuf,
                                                   Wih, Whh, bih, bhh, gsbuf);
    lstm_update<<<NB, 256, 0, stream>>>(gsbuf, hbuf, cbuf);
    for (int net=0; net<2; net++){
      r_kernel<<<dim3(NB, NH/4), 256, 0, stream>>>(mod, sprev, eprev, hbuf, rW[net], rbuf);
      prer_kernel<<<dim3(NB, NPH2/256), 256, 0, stream>>>(rbuf, W1rT[net], b1p[net], prer);
      gemm_fused<0><<<GFULL, 512, 0, stream>>>(modExp, W1exp[net], prer, (void*)m1exp);
      gemm_fused<1><<<GFULL, 512, 0, stream>>>(m1exp, W2exp[net], b2p[net], (void*)m2f);
      logits_main<<<dim3(NB, NS/16), 256, 0, stream>>>(m1exp, m2f, W3[net], b3[net], mask, lgbuf);
      logits_fin<<<NB, 256, 0, stream>>>(lgbuf, out[net], t, net==0 ? sprev : eprev);
    }
  }
}